// Round 1
// baseline (85.770 us; speedup 1.0000x reference)
//
#include <hip/hip_runtime.h>

// Fused Haar-feature + 1x1-conv MLP.
//
// Reference math:
//   f = conv2d(x, 6 fixed 6x6 Haar kernels / 36, SAME pad (2,3))
//   h1 = relu(f @ w1^T + b1)   [6->32]
//   h2 = relu(h1 @ w2^T + b2)  [32->16]
//   out = h2 @ w3^T + b3       [16->2]
//
// All 6 Haar kernels are separable:  k = u_row (x) v_col with u,v in
//   {ones, s=[+,+,+,-,-,-], t=[+,+,-,-,+,+]}:
//   k0 = 1(x)1, k1 = s(x)1, k2 = 1(x)s, k3 = t(x)1, k4 = 1(x)t, k5 = s(x)s
// So: horizontal pass gives streams A(box), S(s), T(t); vertical combines
// give f0=boxV(A), f1=sV(A), f3=tV(A), f2=boxV(S), f5=sV(S), f4=boxV(T).
// The 1/36 normalization is folded into w1 (prep kernel).

#define TW 64
#define TH 16

// Pack weights into d_ws:
//   ws[0   .. 255]: pw1[m][0..7] = {w1[m][0..5]/36, b1[m], 0}   (m = 0..31)
//   ws[256 .. 767]: pw2t[m][o]   = w2[o][m]                      (contiguous in o)
__global__ __launch_bounds__(512) void haar_prep(const float* __restrict__ w1,
                                                 const float* __restrict__ b1,
                                                 const float* __restrict__ w2,
                                                 float* __restrict__ ws) {
  int t = threadIdx.x;
  if (t < 256) {
    int m = t >> 3, k = t & 7;
    float v = 0.f;
    if (k < 6) v = w1[m * 6 + k] * (1.0f / 36.0f);
    else if (k == 6) v = b1[m];
    ws[t] = v;
  }
  // 512 entries of transposed w2
  int m = t >> 4, o = t & 15;
  ws[256 + t] = w2[o * 32 + m];
}

__global__ __launch_bounds__(256) void haar_main(const float* __restrict__ x,
                                                 const float* __restrict__ ws,
                                                 const float* __restrict__ b2,
                                                 const float* __restrict__ w3,
                                                 const float* __restrict__ b3,
                                                 float* __restrict__ out) {
  // input halo tile: (TH+5) x (TW+5), row stride padded to 72 floats
  __shared__ float tile[TH + 5][72];

  const int tid = threadIdx.x;
  const int bc = blockIdx.x * TW;   // output col base
  const int br = blockIdx.y * TH;   // output row base
  const int b  = blockIdx.z;
  const float* xb = x + (size_t)b * (512 * 512);

  // ---- stage input tile (zero-pad OOB); SAME pad: lo=2, hi=3 ----
  #pragma unroll
  for (int e = 0; e < 6; ++e) {
    int idx = tid + e * 256;
    if (idx < (TH + 5) * (TW + 5)) {
      int r = idx / (TW + 5);
      int c = idx - r * (TW + 5);
      int gr = br - 2 + r, gc = bc - 2 + c;
      float v = 0.f;
      if ((unsigned)gr < 512u && (unsigned)gc < 512u) v = xb[gr * 512 + gc];
      tile[r][c] = v;
    }
  }
  __syncthreads();

  const int jl = tid & 63;          // col within tile
  const int r0 = (tid >> 6) * 4;    // first of 4 output rows this thread owns

  // ---- horizontal pass: 9 rows of A/S/T for this thread's column ----
  float A[9], S[9], T[9];
  #pragma unroll
  for (int rr = 0; rr < 9; ++rr) {
    const float* row = &tile[r0 + rr][jl];
    float x0 = row[0], x1 = row[1], x2 = row[2];
    float x3 = row[3], x4 = row[4], x5 = row[5];
    float p01 = x0 + x1, p23 = x2 + x3, p45 = x4 + x5;
    A[rr] = p01 + p23 + p45;          // box
    T[rr] = p01 - p23 + p45;          // [+,+,-,-,+,+]
    S[rr] = (p01 + x2) - (x3 + p45);  // [+,+,+,-,-,-]
  }

  // ---- vertical combines -> 6 features per pixel (x36 scale folded in w1) ----
  float f[6][4];
  #pragma unroll
  for (int p = 0; p < 4; ++p) {
    float ta = A[p] + A[p + 1] + A[p + 2];
    float tb = A[p + 3] + A[p + 4] + A[p + 5];
    f[0][p] = ta + tb;                 // box (x) box
    f[1][p] = ta - tb;                 // s-rows (x) box
    float q01 = A[p] + A[p + 1], q23 = A[p + 2] + A[p + 3], q45 = A[p + 4] + A[p + 5];
    f[3][p] = q01 - q23 + q45;         // t-rows (x) box
    float sa = S[p] + S[p + 1] + S[p + 2];
    float sb = S[p + 3] + S[p + 4] + S[p + 5];
    f[2][p] = sa + sb;                 // box (x) s-cols
    f[5][p] = sa - sb;                 // s-rows (x) s-cols (checker)
    f[4][p] = ((T[p] + T[p + 1]) + (T[p + 2] + T[p + 3])) + (T[p + 4] + T[p + 5]);
  }

  // ---- MLP: stream layer1 -> layer2 accumulation ----
  float h2[16][4];
  #pragma unroll
  for (int o = 0; o < 16; ++o) {
    float bv = b2[o];
    #pragma unroll
    for (int p = 0; p < 4; ++p) h2[o][p] = bv;
  }

  for (int m = 0; m < 32; ++m) {
    const float* pw1 = ws + m * 8;          // uniform -> s_load_dwordx8
    float w0 = pw1[0], w1v = pw1[1], w2v = pw1[2];
    float w3v = pw1[3], w4v = pw1[4], w5v = pw1[5], b1v = pw1[6];
    float t[4];
    #pragma unroll
    for (int p = 0; p < 4; ++p) {
      float a = fmaf(w0, f[0][p], b1v);
      a = fmaf(w1v, f[1][p], a);
      a = fmaf(w2v, f[2][p], a);
      a = fmaf(w3v, f[3][p], a);
      a = fmaf(w4v, f[4][p], a);
      a = fmaf(w5v, f[5][p], a);
      t[p] = fmaxf(a, 0.f);
    }
    const float* pw2 = ws + 256 + m * 16;   // uniform -> s_load_dwordx16
    #pragma unroll
    for (int o = 0; o < 16; ++o) {
      float wv = pw2[o];
      #pragma unroll
      for (int p = 0; p < 4; ++p) h2[o][p] = fmaf(wv, t[p], h2[o][p]);
    }
  }

  // ---- layer3 + store ----
  #pragma unroll
  for (int p = 0; p < 4; ++p) {
    float r[16];
    #pragma unroll
    for (int o = 0; o < 16; ++o) r[o] = fmaxf(h2[o][p], 0.f);
    #pragma unroll
    for (int u = 0; u < 2; ++u) {
      float acc = b3[u];
      #pragma unroll
      for (int o = 0; o < 16; ++o) acc = fmaf(w3[u * 16 + o], r[o], acc);
      size_t oidx = (((size_t)(b * 2 + u) * 512) + (br + r0 + p)) * 512 + (bc + jl);
      out[oidx] = acc;
    }
  }
}

extern "C" void kernel_launch(void* const* d_in, const int* in_sizes, int n_in,
                              void* d_out, int out_size, void* d_ws, size_t ws_size,
                              hipStream_t stream) {
  const float* x  = (const float*)d_in[0];
  const float* w1 = (const float*)d_in[1];
  const float* b1 = (const float*)d_in[2];
  const float* w2 = (const float*)d_in[3];
  const float* b2 = (const float*)d_in[4];
  const float* w3 = (const float*)d_in[5];
  const float* b3 = (const float*)d_in[6];
  float* out = (float*)d_out;
  float* ws  = (float*)d_ws;

  haar_prep<<<1, 512, 0, stream>>>(w1, b1, w2, ws);

  dim3 grid(512 / TW, 512 / TH, 16);   // (8, 32, 16)
  haar_main<<<grid, 256, 0, stream>>>(x, ws, b2, w3, b3, out);
}

// Round 2
// 78.867 us; speedup vs baseline: 1.0875x; 1.0875x over previous
//
#include <hip/hip_runtime.h>

// Fused Haar-feature + 1x1-conv MLP.
//
//   f = conv2d(x, 6 fixed 6x6 Haar kernels / 36, SAME pad (2,3))
//   h1 = relu(f @ w1^T + b1)   [6->32]
//   h2 = relu(h1 @ w2^T + b2)  [32->16]
//   out = h2 @ w3^T + b3       [16->2]
//
// All 6 Haar kernels are separable:  k = u_row (x) v_col with u,v in
//   {ones, s=[+,+,+,-,-,-], t=[+,+,-,-,+,+]}:
//   k0 = 1(x)1, k1 = s(x)1, k2 = 1(x)s, k3 = t(x)1, k4 = 1(x)t, k5 = s(x)s
// Horizontal pass gives streams A(box), S(s), T(t); vertical combines give
// all 6 features. The 1/36 normalization is folded into w1 (prep kernel).
//
// Round-2 changes vs round-1:
//  * __launch_bounds__(256,2): round-1 compiled to 48 VGPRs => h2[16][4]
//    (64 accumulators) was spilled to scratch; raise the cap so the ~110-reg
//    live set stays in registers.
//  * float2 (ext_vector) packed math in the MLP + epilogue so the compiler
//    emits v_pk_fma_f32 (the 157 TF packed-fp32 path; scalar fma is 78.6 TF).

typedef float v2f __attribute__((ext_vector_type(2)));

#define TW 64
#define TH 16

// Pack weights into d_ws:
//   ws[0   .. 255]: pw1[m][0..7] = {w1[m][0..5]/36, b1[m], 0}   (m = 0..31)
//   ws[256 .. 767]: pw2t[m][o]   = w2[o][m]                      (contiguous in o)
__global__ __launch_bounds__(512) void haar_prep(const float* __restrict__ w1,
                                                 const float* __restrict__ b1,
                                                 const float* __restrict__ w2,
                                                 float* __restrict__ ws) {
  int t = threadIdx.x;
  if (t < 256) {
    int m = t >> 3, k = t & 7;
    float v = 0.f;
    if (k < 6) v = w1[m * 6 + k] * (1.0f / 36.0f);
    else if (k == 6) v = b1[m];
    ws[t] = v;
  }
  int m = t >> 4, o = t & 15;
  ws[256 + t] = w2[o * 32 + m];
}

__global__ __launch_bounds__(256, 2) void haar_main(const float* __restrict__ x,
                                                    const float* __restrict__ ws,
                                                    const float* __restrict__ b2,
                                                    const float* __restrict__ w3,
                                                    const float* __restrict__ b3,
                                                    float* __restrict__ out) {
  // input halo tile: (TH+5) x (TW+5), row stride padded to 72 floats
  __shared__ float tile[TH + 5][72];

  const int tid = threadIdx.x;
  const int bc = blockIdx.x * TW;   // output col base
  const int br = blockIdx.y * TH;   // output row base
  const int b  = blockIdx.z;
  const float* xb = x + (size_t)b * (512 * 512);

  // ---- stage input tile (zero-pad OOB); SAME pad: lo=2, hi=3 ----
  #pragma unroll
  for (int e = 0; e < 6; ++e) {
    int idx = tid + e * 256;
    if (idx < (TH + 5) * (TW + 5)) {
      int r = idx / (TW + 5);
      int c = idx - r * (TW + 5);
      int gr = br - 2 + r, gc = bc - 2 + c;
      float v = 0.f;
      if ((unsigned)gr < 512u && (unsigned)gc < 512u) v = xb[gr * 512 + gc];
      tile[r][c] = v;
    }
  }
  __syncthreads();

  const int jl = tid & 63;          // col within tile
  const int r0 = (tid >> 6) * 4;    // first of 4 output rows this thread owns

  // ---- horizontal pass: 9 rows of A/S/T for this thread's column ----
  float A[9], S[9], T[9];
  #pragma unroll
  for (int rr = 0; rr < 9; ++rr) {
    const float* row = &tile[r0 + rr][jl];
    float x0 = row[0], x1 = row[1], x2 = row[2];
    float x3 = row[3], x4 = row[4], x5 = row[5];
    float p01 = x0 + x1, p23 = x2 + x3, p45 = x4 + x5;
    A[rr] = p01 + p23 + p45;          // box
    T[rr] = p01 - p23 + p45;          // [+,+,-,-,+,+]
    S[rr] = (p01 + x2) - (x3 + p45);  // [+,+,+,-,-,-]
  }

  // ---- vertical combines -> 6 features per pixel, packed as pixel-pairs ----
  v2f f2[6][2];
  #pragma unroll
  for (int pp = 0; pp < 2; ++pp) {
    float fs[6][2];
    #pragma unroll
    for (int q = 0; q < 2; ++q) {
      int p = pp * 2 + q;
      float ta = A[p] + A[p + 1] + A[p + 2];
      float tb = A[p + 3] + A[p + 4] + A[p + 5];
      fs[0][q] = ta + tb;                 // box (x) box
      fs[1][q] = ta - tb;                 // s-rows (x) box
      float q01 = A[p] + A[p + 1], q23 = A[p + 2] + A[p + 3], q45 = A[p + 4] + A[p + 5];
      fs[3][q] = q01 - q23 + q45;         // t-rows (x) box
      float sa = S[p] + S[p + 1] + S[p + 2];
      float sb = S[p + 3] + S[p + 4] + S[p + 5];
      fs[2][q] = sa + sb;                 // box (x) s-cols
      fs[5][q] = sa - sb;                 // s-rows (x) s-cols (checker)
      fs[4][q] = ((T[p] + T[p + 1]) + (T[p + 2] + T[p + 3])) + (T[p + 4] + T[p + 5]);
    }
    #pragma unroll
    for (int i = 0; i < 6; ++i) f2[i][pp] = (v2f){fs[i][0], fs[i][1]};
  }

  // ---- MLP: stream layer1 -> layer2 accumulation (packed fp32) ----
  v2f h2[16][2];
  #pragma unroll
  for (int o = 0; o < 16; ++o) {
    float bv = b2[o];
    h2[o][0] = (v2f){bv, bv};
    h2[o][1] = (v2f){bv, bv};
  }

  for (int m = 0; m < 32; ++m) {
    const float* pw1 = ws + m * 8;          // uniform -> s_load_dwordx8
    float w0 = pw1[0], w1v = pw1[1], w2v = pw1[2];
    float w3v = pw1[3], w4v = pw1[4], w5v = pw1[5], b1v = pw1[6];
    v2f t2[2];
    #pragma unroll
    for (int pp = 0; pp < 2; ++pp) {
      v2f a = (v2f){b1v, b1v};
      a += (v2f){w0, w0}   * f2[0][pp];
      a += (v2f){w1v, w1v} * f2[1][pp];
      a += (v2f){w2v, w2v} * f2[2][pp];
      a += (v2f){w3v, w3v} * f2[3][pp];
      a += (v2f){w4v, w4v} * f2[4][pp];
      a += (v2f){w5v, w5v} * f2[5][pp];
      t2[pp] = __builtin_elementwise_max(a, (v2f){0.f, 0.f});
    }
    const float* pw2 = ws + 256 + m * 16;   // uniform -> s_load_dwordx16
    #pragma unroll
    for (int o = 0; o < 16; ++o) {
      float wv = pw2[o];
      v2f wvv = (v2f){wv, wv};
      h2[o][0] += wvv * t2[0];
      h2[o][1] += wvv * t2[1];
    }
  }

  // ---- layer3 + store (packed) ----
  v2f acc0[2], acc1[2];
  acc0[0] = (v2f){b3[0], b3[0]}; acc0[1] = acc0[0];
  acc1[0] = (v2f){b3[1], b3[1]}; acc1[1] = acc1[0];
  #pragma unroll
  for (int o = 0; o < 16; ++o) {
    v2f ra = __builtin_elementwise_max(h2[o][0], (v2f){0.f, 0.f});
    v2f rb = __builtin_elementwise_max(h2[o][1], (v2f){0.f, 0.f});
    float wa = w3[o], wb = w3[16 + o];
    acc0[0] += (v2f){wa, wa} * ra;
    acc0[1] += (v2f){wa, wa} * rb;
    acc1[0] += (v2f){wb, wb} * ra;
    acc1[1] += (v2f){wb, wb} * rb;
  }

  const int colg = bc + jl;
  size_t base0 = (((size_t)(b * 2 + 0) * 512) + (br + r0)) * 512 + colg;
  size_t base1 = (((size_t)(b * 2 + 1) * 512) + (br + r0)) * 512 + colg;
  out[base0 + 0 * 512] = acc0[0].x;
  out[base0 + 1 * 512] = acc0[0].y;
  out[base0 + 2 * 512] = acc0[1].x;
  out[base0 + 3 * 512] = acc0[1].y;
  out[base1 + 0 * 512] = acc1[0].x;
  out[base1 + 1 * 512] = acc1[0].y;
  out[base1 + 2 * 512] = acc1[1].x;
  out[base1 + 3 * 512] = acc1[1].y;
}

extern "C" void kernel_launch(void* const* d_in, const int* in_sizes, int n_in,
                              void* d_out, int out_size, void* d_ws, size_t ws_size,
                              hipStream_t stream) {
  const float* x  = (const float*)d_in[0];
  const float* w1 = (const float*)d_in[1];
  const float* b1 = (const float*)d_in[2];
  const float* w2 = (const float*)d_in[3];
  const float* b2 = (const float*)d_in[4];
  const float* w3 = (const float*)d_in[5];
  const float* b3 = (const float*)d_in[6];
  float* out = (float*)d_out;
  float* ws  = (float*)d_ws;

  haar_prep<<<1, 512, 0, stream>>>(w1, b1, w2, ws);

  dim3 grid(512 / TW, 512 / TH, 16);   // (8, 32, 16)
  haar_main<<<grid, 256, 0, stream>>>(x, ws, b2, w3, b3, out);
}